// Round 9
// baseline (823.922 us; speedup 1.0000x reference)
//
#include <hip/hip_runtime.h>
#include <hip/hip_cooperative_groups.h>

namespace cg = cooperative_groups;

// GraphSAGE 3-layer encoder. R9: cooperative mega-kernel with occupancy-sized
// grid + typed launch + multi-kernel fallback on launch failure.
// Phases: zero cnt -> build (ELL fill + bf16 casts) -> [gather -> GEMM] x3 ->
// bsearch mean-pool. All phases grid-stride (any grid size correct).
#define N_NODES 50000
#define NP 50048          // padded to 782*64 rows
#define N_EDGES 800000
#define N_GRAPHS 512
#define F 128
#define ELLW 64           // Poisson(16): P(deg>=64) ~ e^-125
#define NTILES (NP / 64)  // 782
#define CU_COUNT 256

typedef __bf16 bf16x8 __attribute__((ext_vector_type(8)));
typedef float f32x4 __attribute__((ext_vector_type(4)));
typedef unsigned short ushort_t;
typedef unsigned int uint_t;

__device__ inline ushort_t f2bf(float f) {  // RTNE
    uint_t u = __float_as_uint(f);
    u += 0x7FFFu + ((u >> 16) & 1u);
    return (ushort_t)(u >> 16);
}
__device__ inline float bf2f(ushort_t u) {
    return __uint_as_float(((uint_t)u) << 16);
}
__device__ inline uint_t pack2(float a, float b) {
    return (uint_t)f2bf(a) | ((uint_t)f2bf(b) << 16);
}
__device__ inline void addrow(float* a, uint4 v) {
    a[0] += __uint_as_float(v.x << 16); a[1] += __uint_as_float(v.x & 0xFFFF0000u);
    a[2] += __uint_as_float(v.y << 16); a[3] += __uint_as_float(v.y & 0xFFFF0000u);
    a[4] += __uint_as_float(v.z << 16); a[5] += __uint_as_float(v.z & 0xFFFF0000u);
    a[6] += __uint_as_float(v.w << 16); a[7] += __uint_as_float(v.w & 0xFFFF0000u);
}

// ---- device phases (shared by mega + fallback kernels) ----
__device__ __forceinline__ void dev_build(
    const float* __restrict__ x,
    const float* __restrict__ W1l, const float* __restrict__ W1r,
    const float* __restrict__ W2l, const float* __restrict__ W2r,
    const float* __restrict__ W3l, const float* __restrict__ W3r,
    const int* __restrict__ src, const int* __restrict__ dst,
    ushort_t* __restrict__ X, ushort_t* __restrict__ WB,
    int* __restrict__ cnt, ushort_t* __restrict__ ell,
    int gt, int stride) {
    for (int e = gt; e < N_EDGES; e += stride) {
        int d = dst[e];
        int pos = atomicAdd(&cnt[d], 1);
        if (pos < ELLW) ell[((size_t)d << 6) + pos] = (ushort_t)src[e];
    }
    for (int gidx = gt; gidx < NP * 16; gidx += stride) {
        int i = gidx * 8;
        uint4 o = make_uint4(0, 0, 0, 0);
        if (i < N_NODES * F) {  // boundary 8-aligned: no straddle
            float4 v0 = *(const float4*)&x[i];
            float4 v1 = *(const float4*)&x[i + 4];
            o = make_uint4(pack2(v0.x, v0.y), pack2(v0.z, v0.w),
                           pack2(v1.x, v1.y), pack2(v1.z, v1.w));
        }
        *(uint4*)&X[i] = o;
    }
    for (int idx = gt; idx < 12288; idx += stride) {  // 6 matrices * 2048 x8
        int m = idx >> 11;
        int o = (idx & 2047) * 8;
        const float* s = W1l;
        if (m == 1) s = W1r; else if (m == 2) s = W2l; else if (m == 3) s = W2r;
        else if (m == 4) s = W3l; else if (m == 5) s = W3r;
        float4 v0 = *(const float4*)&s[o];
        float4 v1 = *(const float4*)&s[o + 4];
        *(uint4*)&WB[m * 16384 + o] =
            make_uint4(pack2(v0.x, v0.y), pack2(v0.z, v0.w),
                       pack2(v1.x, v1.y), pack2(v1.z, v1.w));
    }
}

__device__ __forceinline__ void dev_gather(const ushort_t* __restrict__ hin,
                                           const ushort_t* __restrict__ ell,
                                           const int* __restrict__ cnt,
                                           ushort_t* __restrict__ agg,
                                           int gt, int stride) {
    int lane16 = gt & 15;
    const uint4* h4 = (const uint4*)hin;
    for (int n = gt >> 4; n < N_NODES; n += stride >> 4) {
        int deg = min(cnt[n], ELLW);
        const ushort_t* el = ell + ((size_t)n << 6);
        float ax[8], ay[8];
#pragma unroll
        for (int j = 0; j < 8; j++) { ax[j] = 0.f; ay[j] = 0.f; }
        int i = 0;
        for (; i + 4 <= deg; i += 4) {
            int s0 = el[i], s1 = el[i + 1], s2 = el[i + 2], s3 = el[i + 3];
            uint4 v0 = h4[(size_t)s0 * 16 + lane16];
            uint4 v1 = h4[(size_t)s1 * 16 + lane16];
            uint4 v2 = h4[(size_t)s2 * 16 + lane16];
            uint4 v3 = h4[(size_t)s3 * 16 + lane16];
            addrow(ax, v0); addrow(ay, v1); addrow(ax, v2); addrow(ay, v3);
        }
        for (; i < deg; i++) {
            uint4 v0 = h4[(size_t)el[i] * 16 + lane16];
            addrow(ax, v0);
        }
        float sc = 1.0f / fmaxf((float)deg, 1.0f);
        ((uint4*)agg)[(size_t)n * 16 + lane16] = make_uint4(
            pack2((ax[0] + ay[0]) * sc, (ax[1] + ay[1]) * sc),
            pack2((ax[2] + ay[2]) * sc, (ax[3] + ay[3]) * sc),
            pack2((ax[4] + ay[4]) * sc, (ax[5] + ay[5]) * sc),
            pack2((ax[6] + ay[6]) * sc, (ax[7] + ay[7]) * sc));
    }
}

// dual-GEMM: one 64-row tile per block iteration, grid-stride over tiles.
__device__ __forceinline__ void dev_linear(const ushort_t* __restrict__ agg,
                                           const ushort_t* __restrict__ hin,
                                           const ushort_t* __restrict__ Wl,
                                           const ushort_t* __restrict__ Wr,
                                           const float* __restrict__ bias,
                                           ushort_t* __restrict__ hout,
                                           int bid, int nblocks, int t,
                                           ushort_t* Hlds, ushort_t* Blds) {
    int w = t >> 6;
    int lane = t & 63;
    int wm = (w & 1) * 32;
    int wn = (w >> 1) * 64;
    int lrow = lane & 15;
    int kg = lane >> 4;
    int quad = lane >> 4;

    for (int tile = bid; tile < NTILES; tile += nblocks) {
        int bm = tile * 64;
        f32x4 acc[2][4];
#pragma unroll
        for (int i = 0; i < 2; i++)
#pragma unroll
            for (int j = 0; j < 4; j++) acc[i][j] = (f32x4){0.f, 0.f, 0.f, 0.f};

#pragma unroll
        for (int iter = 0; iter < 4; iter++) {
            const ushort_t* A = (iter < 2) ? agg : hin;
            const ushort_t* W = (iter < 2) ? Wl : Wr;
            int k0 = (iter & 1) * 64;

            __syncthreads();  // LDS safe to overwrite (block-uniform loop)
#pragma unroll
            for (int p = 0; p < 2; p++) {
                int chunkA = p * 4 + w;
                const ushort_t* gA = A + (size_t)(bm + lane) * F + k0 + chunkA * 8;
                ushort_t* lA = Hlds + (size_t)(chunkA * 64) * 8;
                __builtin_amdgcn_global_load_lds(
                    (const __attribute__((address_space(1))) void*)gA,
                    (__attribute__((address_space(3))) void*)lA, 16, 0, 0);
            }
#pragma unroll
            for (int p = 0; p < 4; p++) {
                int chunkB = p * 2 + (w >> 1);
                int rbase = (w & 1) * 64;
                const ushort_t* gB = W + (size_t)(rbase + lane) * F + k0 + chunkB * 8;
                ushort_t* lB = Blds + (size_t)(chunkB * 128 + rbase) * 8;
                __builtin_amdgcn_global_load_lds(
                    (const __attribute__((address_space(1))) void*)gB,
                    (__attribute__((address_space(3))) void*)lB, 16, 0, 0);
            }
            __syncthreads();

#pragma unroll
            for (int ks = 0; ks < 2; ks++) {
                bf16x8 af[2], bfr[4];
#pragma unroll
                for (int i = 0; i < 2; i++)
                    af[i] = *(const bf16x8*)(Hlds +
                        (size_t)((ks * 4 + kg) * 64 + wm + i * 16 + lrow) * 8);
#pragma unroll
                for (int j = 0; j < 4; j++)
                    bfr[j] = *(const bf16x8*)(Blds +
                        (size_t)((ks * 4 + kg) * 128 + wn + j * 16 + lrow) * 8);
#pragma unroll
                for (int i = 0; i < 2; i++)
#pragma unroll
                    for (int j = 0; j < 4; j++)
                        acc[i][j] = __builtin_amdgcn_mfma_f32_16x16x32_bf16(
                            af[i], bfr[j], acc[i][j], 0, 0, 0);
            }
        }

#pragma unroll
        for (int j = 0; j < 4; j++) {
            int c = wn + j * 16 + lrow;
            float bj = bias[c];
#pragma unroll
            for (int i = 0; i < 2; i++) {
#pragma unroll
                for (int r = 0; r < 4; r++) {
                    int row = bm + wm + i * 16 + quad * 4 + r;
                    if (row < N_NODES) {
                        float v = fmaxf(acc[i][j][r] + bj, 0.0f);
                        hout[(size_t)row * F + c] = f2bf(v);
                    }
                }
            }
        }
    }
}

// pool: one block per graph (grid-stride), 256 threads (2 halves per column).
__device__ __forceinline__ void dev_pool(const ushort_t* __restrict__ h,
                                         const int* __restrict__ batch,
                                         float* __restrict__ out,
                                         int bid, int nblocks, int t,
                                         float* red) {
    int col = t & 127;
    int half = t >> 7;
    for (int g = bid; g < N_GRAPHS; g += nblocks) {
        int lo = 0, hi = N_NODES;
        while (lo < hi) {
            int m = (lo + hi) >> 1;
            if (batch[m] < g) lo = m + 1; else hi = m;
        }
        int start = lo;
        lo = start; hi = N_NODES;
        while (lo < hi) {
            int m = (lo + hi) >> 1;
            if (batch[m] < g + 1) lo = m + 1; else hi = m;
        }
        int end = lo;
        float s = 0.0f;
        for (int n = start + half; n < end; n += 2)
            s += bf2f(h[(size_t)n * F + col]);
        if (half) red[col] = s;
        __syncthreads();
        if (!half)
            out[g * F + col] = (s + red[col]) / fmaxf((float)(end - start), 1.0f);
        __syncthreads();  // red reuse across loop iterations
    }
}

// ---- cooperative mega-kernel ----
__global__ __launch_bounds__(256, 4) void k_mega(
    const float* __restrict__ x, const int* __restrict__ ei,
    const int* __restrict__ batch,
    const float* __restrict__ W1l, const float* __restrict__ W1r,
    const float* __restrict__ b1,
    const float* __restrict__ W2l, const float* __restrict__ W2r,
    const float* __restrict__ b2,
    const float* __restrict__ W3l, const float* __restrict__ W3r,
    const float* __restrict__ b3,
    float* __restrict__ out, void* __restrict__ ws) {
    cg::grid_group grid = cg::this_grid();
    __shared__ uint4 Hlds4[512];    // 8 KB (reused as pool reduction buffer)
    __shared__ uint4 Blds4[1024];   // 16 KB
    ushort_t* Hlds = (ushort_t*)Hlds4;
    ushort_t* Blds = (ushort_t*)Blds4;

    ushort_t* X   = (ushort_t*)ws;
    ushort_t* HA  = X + (size_t)NP * F;
    ushort_t* HB  = HA + (size_t)NP * F;
    ushort_t* AGG = HB + (size_t)NP * F;
    ushort_t* WB  = AGG + (size_t)NP * F;
    int* cnt = (int*)(WB + 6 * 16384);
    ushort_t* ell = (ushort_t*)(cnt + 50176);

    int bid = blockIdx.x;
    int nblocks = gridDim.x;
    int t = threadIdx.x;
    int gt = bid * 256 + t;
    int stride = nblocks * 256;

    for (int i = gt; i < 12544; i += stride)
        *(int4*)&cnt[i * 4] = make_int4(0, 0, 0, 0);
    grid.sync();

    dev_build(x, W1l, W1r, W2l, W2r, W3l, W3r, ei, ei + N_EDGES,
              X, WB, cnt, ell, gt, stride);
    grid.sync();

    dev_gather(X, ell, cnt, AGG, gt, stride);
    grid.sync();
    dev_linear(AGG, X, WB, WB + 16384, b1, HA, bid, nblocks, t, Hlds, Blds);
    grid.sync();
    dev_gather(HA, ell, cnt, AGG, gt, stride);
    grid.sync();
    dev_linear(AGG, HA, WB + 2 * 16384, WB + 3 * 16384, b2, HB, bid, nblocks,
               t, Hlds, Blds);
    grid.sync();
    dev_gather(HB, ell, cnt, AGG, gt, stride);
    grid.sync();
    dev_linear(AGG, HB, WB + 4 * 16384, WB + 5 * 16384, b3, HA, bid, nblocks,
               t, Hlds, Blds);
    grid.sync();

    dev_pool(HA, batch, out, bid, nblocks, t, (float*)Hlds4);
}

// ---- fallback kernels (same device code, separate dispatches) ----
__global__ __launch_bounds__(256) void k_buildF(
    const float* __restrict__ x,
    const float* __restrict__ W1l, const float* __restrict__ W1r,
    const float* __restrict__ W2l, const float* __restrict__ W2r,
    const float* __restrict__ W3l, const float* __restrict__ W3r,
    const int* __restrict__ ei,
    ushort_t* __restrict__ X, ushort_t* __restrict__ WB,
    int* __restrict__ cnt, ushort_t* __restrict__ ell) {
    int gt = blockIdx.x * 256 + threadIdx.x;
    dev_build(x, W1l, W1r, W2l, W2r, W3l, W3r, ei, ei + N_EDGES,
              X, WB, cnt, ell, gt, gridDim.x * 256);
}

__global__ __launch_bounds__(256) void k_gatherF(const ushort_t* __restrict__ hin,
                                                 const ushort_t* __restrict__ ell,
                                                 const int* __restrict__ cnt,
                                                 ushort_t* __restrict__ agg) {
    int gt = blockIdx.x * 256 + threadIdx.x;
    dev_gather(hin, ell, cnt, agg, gt, gridDim.x * 256);
}

__global__ __launch_bounds__(256) void k_linearF(const ushort_t* __restrict__ agg,
                                                 const ushort_t* __restrict__ hin,
                                                 const ushort_t* __restrict__ Wl,
                                                 const ushort_t* __restrict__ Wr,
                                                 const float* __restrict__ bias,
                                                 ushort_t* __restrict__ hout) {
    __shared__ uint4 Hlds4[512];
    __shared__ uint4 Blds4[1024];
    dev_linear(agg, hin, Wl, Wr, bias, hout, blockIdx.x, gridDim.x,
               threadIdx.x, (ushort_t*)Hlds4, (ushort_t*)Blds4);
}

__global__ __launch_bounds__(256) void k_poolF(const ushort_t* __restrict__ h,
                                               const int* __restrict__ batch,
                                               float* __restrict__ out) {
    __shared__ float red[128];
    dev_pool(h, batch, out, blockIdx.x, gridDim.x, threadIdx.x, red);
}

extern "C" void kernel_launch(void* const* d_in, const int* in_sizes, int n_in,
                              void* d_out, int out_size, void* d_ws, size_t ws_size,
                              hipStream_t stream) {
    const float* x   = (const float*)d_in[0];
    const int*   ei  = (const int*)d_in[1];
    const int* batch = (const int*)d_in[2];
    const float* W1l = (const float*)d_in[3];
    const float* W1r = (const float*)d_in[4];
    const float* b1  = (const float*)d_in[5];
    const float* W2l = (const float*)d_in[6];
    const float* W2r = (const float*)d_in[7];
    const float* b2  = (const float*)d_in[8];
    const float* W3l = (const float*)d_in[9];
    const float* W3r = (const float*)d_in[10];
    const float* b3  = (const float*)d_in[11];
    float* out = (float*)d_out;
    void* wsv = d_ws;

    // occupancy-sized cooperative grid (host query, capture-safe)
    int nb = 0;
    hipError_t oe = hipOccupancyMaxActiveBlocksPerMultiprocessor(&nb, k_mega, 256, 0);
    bool coop_ok = (oe == hipSuccess && nb >= 1);
    if (coop_ok) {
        int grid = nb * CU_COUNT;
        if (grid > 2048) grid = 2048;
        void* args[] = {
            (void*)&x, (void*)&ei, (void*)&batch,
            (void*)&W1l, (void*)&W1r, (void*)&b1,
            (void*)&W2l, (void*)&W2r, (void*)&b2,
            (void*)&W3l, (void*)&W3r, (void*)&b3,
            (void*)&out, (void*)&wsv};
        hipError_t rc = hipLaunchCooperativeKernel(k_mega, dim3(grid), dim3(256),
                                                   args, 0, stream);
        coop_ok = (rc == hipSuccess);
    }

    if (!coop_ok) {
        // fallback: proven multi-kernel path
        ushort_t* X   = (ushort_t*)d_ws;
        ushort_t* HA  = X + (size_t)NP * F;
        ushort_t* HB  = HA + (size_t)NP * F;
        ushort_t* AGG = HB + (size_t)NP * F;
        ushort_t* WB  = AGG + (size_t)NP * F;
        int* cnt = (int*)(WB + 6 * 16384);
        ushort_t* ell = (ushort_t*)(cnt + 50176);

        hipMemsetAsync(cnt, 0, 50176 * sizeof(int), stream);
        k_buildF<<<1024, 256, 0, stream>>>(x, W1l, W1r, W2l, W2r, W3l, W3r,
                                           ei, X, WB, cnt, ell);
        k_gatherF<<<3125, 256, 0, stream>>>(X, ell, cnt, AGG);
        k_linearF<<<NTILES, 256, 0, stream>>>(AGG, X, WB, WB + 16384, b1, HA);
        k_gatherF<<<3125, 256, 0, stream>>>(HA, ell, cnt, AGG);
        k_linearF<<<NTILES, 256, 0, stream>>>(AGG, HA, WB + 2 * 16384,
                                              WB + 3 * 16384, b2, HB);
        k_gatherF<<<3125, 256, 0, stream>>>(HB, ell, cnt, AGG);
        k_linearF<<<NTILES, 256, 0, stream>>>(AGG, HB, WB + 4 * 16384,
                                              WB + 5 * 16384, b3, HA);
        k_poolF<<<N_GRAPHS, 256, 0, stream>>>(HA, batch, out);
    }
}

// Round 10
// 313.389 us; speedup vs baseline: 2.6291x; 2.6291x over previous
//
#include <hip/hip_runtime.h>

// GraphSAGE 3-layer encoder. R10: best-known multi-kernel assembly.
// Merged build (ELL fill + bf16 casts, R6) -> [R5-pattern gather (ILP-4,
// scalar idx) -> BK=128 MFMA dual-GEMM (2 stages, 4 barriers)] x3 -> pool.
#define N_NODES 50000
#define NP 50048          // padded to 782*64 rows
#define N_EDGES 800000
#define N_GRAPHS 512
#define F 128
#define ELLW 64           // Poisson(16): P(deg>=64) ~ e^-125

#define FILL_BLOCKS 3125    // N_EDGES/256
#define CASTX_BLOCKS 3128   // NP*F/8/256
#define CASTW_BLOCKS 48     // 6*16384/8/256

typedef __bf16 bf16x8 __attribute__((ext_vector_type(8)));
typedef float f32x4 __attribute__((ext_vector_type(4)));
typedef unsigned short ushort_t;
typedef unsigned int uint_t;

__device__ inline ushort_t f2bf(float f) {  // RTNE
    uint_t u = __float_as_uint(f);
    u += 0x7FFFu + ((u >> 16) & 1u);
    return (ushort_t)(u >> 16);
}
__device__ inline float bf2f(ushort_t u) {
    return __uint_as_float(((uint_t)u) << 16);
}
__device__ inline uint_t pack2(float a, float b) {
    return (uint_t)f2bf(a) | ((uint_t)f2bf(b) << 16);
}
__device__ inline void addrow(float* a, uint4 v) {
    a[0] += __uint_as_float(v.x << 16); a[1] += __uint_as_float(v.x & 0xFFFF0000u);
    a[2] += __uint_as_float(v.y << 16); a[3] += __uint_as_float(v.y & 0xFFFF0000u);
    a[4] += __uint_as_float(v.z << 16); a[5] += __uint_as_float(v.z & 0xFFFF0000u);
    a[6] += __uint_as_float(v.w << 16); a[7] += __uint_as_float(v.w & 0xFFFF0000u);
}

// ---- merged build: ELL fill (latency-bound) overlapped with casts (BW) ----
__global__ __launch_bounds__(256) void k_build(
    const float* __restrict__ x,
    const float* __restrict__ w0, const float* __restrict__ w1,
    const float* __restrict__ w2, const float* __restrict__ w3,
    const float* __restrict__ w4, const float* __restrict__ w5,
    const int* __restrict__ src, const int* __restrict__ dst,
    ushort_t* __restrict__ X, ushort_t* __restrict__ WB,
    int* __restrict__ cnt, ushort_t* __restrict__ ell) {
    int b = blockIdx.x;
    int t = threadIdx.x;
    if (b < FILL_BLOCKS) {
        int e = b * 256 + t;
        int d = dst[e];
        int pos = atomicAdd(&cnt[d], 1);
        if (pos < ELLW) ell[((size_t)d << 6) + pos] = (ushort_t)src[e];
    } else if (b < FILL_BLOCKS + CASTX_BLOCKS) {
        int i = ((b - FILL_BLOCKS) * 256 + t) * 8;
        uint4 o = make_uint4(0, 0, 0, 0);
        if (i < N_NODES * F) {  // boundary 8-aligned: no straddle
            float4 v0 = *(const float4*)&x[i];
            float4 v1 = *(const float4*)&x[i + 4];
            o = make_uint4(pack2(v0.x, v0.y), pack2(v0.z, v0.w),
                           pack2(v1.x, v1.y), pack2(v1.z, v1.w));
        }
        *(uint4*)&X[i] = o;
    } else {
        int idx = (b - FILL_BLOCKS - CASTX_BLOCKS) * 256 + t;  // 8-elem groups
        int m = idx >> 11;
        int o = (idx & 2047) * 8;
        const float* s = w0;
        if (m == 1) s = w1; else if (m == 2) s = w2; else if (m == 3) s = w3;
        else if (m == 4) s = w4; else if (m == 5) s = w5;
        float4 v0 = *(const float4*)&s[o];
        float4 v1 = *(const float4*)&s[o + 4];
        *(uint4*)&WB[m * 16384 + o] =
            make_uint4(pack2(v0.x, v0.y), pack2(v0.z, v0.w),
                       pack2(v1.x, v1.y), pack2(v1.z, v1.w));
    }
}

// ---- gather-mean: 16 lanes/node, ILP-4, scalar ushort index loads (R5) ----
__global__ __launch_bounds__(256) void k_gather(const ushort_t* __restrict__ h,
                                                const ushort_t* __restrict__ ell,
                                                const int* __restrict__ cnt,
                                                ushort_t* __restrict__ agg) {
    int t = blockIdx.x * 256 + threadIdx.x;
    int n = t >> 4;
    int lane16 = t & 15;
    if (n >= N_NODES) return;
    int deg = min(cnt[n], ELLW);
    const ushort_t* el = ell + ((size_t)n << 6);
    const uint4* h4 = (const uint4*)h;
    float ax[8], ay[8];
#pragma unroll
    for (int j = 0; j < 8; j++) { ax[j] = 0.f; ay[j] = 0.f; }
    int i = 0;
    for (; i + 4 <= deg; i += 4) {
        int s0 = el[i], s1 = el[i + 1], s2 = el[i + 2], s3 = el[i + 3];
        uint4 v0 = h4[(size_t)s0 * 16 + lane16];
        uint4 v1 = h4[(size_t)s1 * 16 + lane16];
        uint4 v2 = h4[(size_t)s2 * 16 + lane16];
        uint4 v3 = h4[(size_t)s3 * 16 + lane16];
        addrow(ax, v0); addrow(ay, v1); addrow(ax, v2); addrow(ay, v3);
    }
    for (; i < deg; i++) {
        uint4 v0 = h4[(size_t)el[i] * 16 + lane16];
        addrow(ax, v0);
    }
    float sc = 1.0f / fmaxf((float)deg, 1.0f);
    ((uint4*)agg)[(size_t)n * 16 + lane16] = make_uint4(
        pack2((ax[0] + ay[0]) * sc, (ax[1] + ay[1]) * sc),
        pack2((ax[2] + ay[2]) * sc, (ax[3] + ay[3]) * sc),
        pack2((ax[4] + ay[4]) * sc, (ax[5] + ay[5]) * sc),
        pack2((ax[6] + ay[6]) * sc, (ax[7] + ay[7]) * sc));
}

// ---- MFMA linear, BK=128: 2 stages (agg@Wl, then h@Wr), 4 barriers total.
// BM=64, BN=128; 782 blocks, 4 waves 2x2 (wave 32x64 via 2x4 MFMAs x4 ksteps).
// LDS: A 16 KB + B 32 KB = 48 KB, [kchunk][row]x16B GLL-compatible layout.
__global__ __launch_bounds__(256) void k_linear(const ushort_t* __restrict__ agg,
                                                const ushort_t* h,  // may alias out
                                                const ushort_t* __restrict__ Wl,
                                                const ushort_t* __restrict__ Wr,
                                                const float* __restrict__ bias,
                                                ushort_t* out) {
    __shared__ uint4 Alds4[1024];   // 16 KB: 64 rows x 128 k bf16
    __shared__ uint4 Blds4[2048];   // 32 KB: 128 rows x 128 k bf16
    ushort_t* Alds = (ushort_t*)Alds4;
    ushort_t* Blds = (ushort_t*)Blds4;

    int t = threadIdx.x;
    int w = t >> 6;
    int lane = t & 63;
    int bm = blockIdx.x * 64;
    int wm = (w & 1) * 32;
    int wn = (w >> 1) * 64;
    int lrow = lane & 15;
    int kg = lane >> 4;

    f32x4 acc[2][4];
#pragma unroll
    for (int i = 0; i < 2; i++)
#pragma unroll
        for (int j = 0; j < 4; j++) acc[i][j] = (f32x4){0.f, 0.f, 0.f, 0.f};

#pragma unroll
    for (int iter = 0; iter < 2; iter++) {
        const ushort_t* A = iter ? h : agg;
        const ushort_t* W = iter ? Wr : Wl;

        __syncthreads();  // LDS safe to overwrite
        // A: 1024 slots of 16B, 4/thread. chunk = p*4+w, row = lane.
#pragma unroll
        for (int p = 0; p < 4; p++) {
            int chunkA = p * 4 + w;
            const ushort_t* gA = A + (size_t)(bm + lane) * F + chunkA * 8;
            ushort_t* lA = Alds + (size_t)(chunkA * 64) * 8;
            __builtin_amdgcn_global_load_lds(
                (const __attribute__((address_space(1))) void*)gA,
                (__attribute__((address_space(3))) void*)lA, 16, 0, 0);
        }
        // B: 2048 slots of 16B, 8/thread. chunk = p*2+(w>>1), row = (w&1)*64+lane.
#pragma unroll
        for (int p = 0; p < 8; p++) {
            int chunkB = p * 2 + (w >> 1);
            int rbase = (w & 1) * 64;
            const ushort_t* gB = W + (size_t)(rbase + lane) * F + chunkB * 8;
            ushort_t* lB = Blds + (size_t)(chunkB * 128 + rbase) * 8;
            __builtin_amdgcn_global_load_lds(
                (const __attribute__((address_space(1))) void*)gB,
                (__attribute__((address_space(3))) void*)lB, 16, 0, 0);
        }
        __syncthreads();

#pragma unroll
        for (int ks = 0; ks < 4; ks++) {
            bf16x8 af[2], bfr[4];
#pragma unroll
            for (int i = 0; i < 2; i++)
                af[i] = *(const bf16x8*)(Alds +
                    (size_t)((ks * 4 + kg) * 64 + wm + i * 16 + lrow) * 8);
#pragma unroll
            for (int j = 0; j < 4; j++)
                bfr[j] = *(const bf16x8*)(Blds +
                    (size_t)((ks * 4 + kg) * 128 + wn + j * 16 + lrow) * 8);
#pragma unroll
            for (int i = 0; i < 2; i++)
#pragma unroll
                for (int j = 0; j < 4; j++)
                    acc[i][j] = __builtin_amdgcn_mfma_f32_16x16x32_bf16(
                        af[i], bfr[j], acc[i][j], 0, 0, 0);
        }
    }

    // epilogue: C/D map col=lane&15, row=(lane>>4)*4+reg
    int quad = lane >> 4;
#pragma unroll
    for (int j = 0; j < 4; j++) {
        int c = wn + j * 16 + lrow;
        float bj = bias[c];
#pragma unroll
        for (int i = 0; i < 2; i++) {
#pragma unroll
            for (int r = 0; r < 4; r++) {
                int row = bm + wm + i * 16 + quad * 4 + r;
                if (row < N_NODES) {
                    float v = fmaxf(acc[i][j][r] + bj, 0.0f);
                    out[(size_t)row * F + c] = f2bf(v);
                }
            }
        }
    }
}

// ---- mean pool: block per graph, 256 thr (2 halves/col), bsearch ----
__global__ __launch_bounds__(256) void k_pool(const ushort_t* __restrict__ h,
                                              const int* __restrict__ batch,
                                              float* __restrict__ out) {
    __shared__ float red[128];
    int g = blockIdx.x;
    int t = threadIdx.x;
    int col = t & 127;
    int half = t >> 7;
    int lo = 0, hi = N_NODES;
    while (lo < hi) {
        int m = (lo + hi) >> 1;
        if (batch[m] < g) lo = m + 1; else hi = m;
    }
    int start = lo;
    lo = start; hi = N_NODES;
    while (lo < hi) {
        int m = (lo + hi) >> 1;
        if (batch[m] < g + 1) lo = m + 1; else hi = m;
    }
    int end = lo;
    float s = 0.0f;
    for (int n = start + half; n < end; n += 2)
        s += bf2f(h[(size_t)n * F + col]);
    if (half) red[col] = s;
    __syncthreads();
    if (!half)
        out[g * F + col] = (s + red[col]) / fmaxf((float)(end - start), 1.0f);
}

extern "C" void kernel_launch(void* const* d_in, const int* in_sizes, int n_in,
                              void* d_out, int out_size, void* d_ws, size_t ws_size,
                              hipStream_t stream) {
    const float* x   = (const float*)d_in[0];
    const int*   ei  = (const int*)d_in[1];
    const int* batch = (const int*)d_in[2];
    const float* W1l = (const float*)d_in[3];
    const float* W1r = (const float*)d_in[4];
    const float* b1  = (const float*)d_in[5];
    const float* W2l = (const float*)d_in[6];
    const float* W2r = (const float*)d_in[7];
    const float* b2  = (const float*)d_in[8];
    const float* W3l = (const float*)d_in[9];
    const float* W3r = (const float*)d_in[10];
    const float* b3  = (const float*)d_in[11];
    float* out = (float*)d_out;

    const int* src = ei;
    const int* dst = ei + N_EDGES;

    // ws layout (~46 MB)
    ushort_t* X   = (ushort_t*)d_ws;          // NP*128 bf16
    ushort_t* HA  = X + (size_t)NP * F;
    ushort_t* HB  = HA + (size_t)NP * F;
    ushort_t* AGG = HB + (size_t)NP * F;
    ushort_t* WB  = AGG + (size_t)NP * F;     // 6*16384 bf16
    int* cnt = (int*)(WB + 6 * 16384);        // 50176 ints
    ushort_t* ell = (ushort_t*)(cnt + 50176); // 50000*64 ushort

    const ushort_t* Wb1l = WB;
    const ushort_t* Wb1r = WB + 16384;
    const ushort_t* Wb2l = WB + 2 * 16384;
    const ushort_t* Wb2r = WB + 3 * 16384;
    const ushort_t* Wb3l = WB + 4 * 16384;
    const ushort_t* Wb3r = WB + 5 * 16384;

    hipMemsetAsync(cnt, 0, 50176 * sizeof(int), stream);
    k_build<<<FILL_BLOCKS + CASTX_BLOCKS + CASTW_BLOCKS, 256, 0, stream>>>(
        x, W1l, W1r, W2l, W2r, W3l, W3r, src, dst, X, WB, cnt, ell);

    const int gatherBlocks = (N_NODES * 16 + 255) / 256;  // 3125
    const int linearBlocks = NP / 64;                     // 782

    k_gather<<<gatherBlocks, 256, 0, stream>>>(X, ell, cnt, AGG);
    k_linear<<<linearBlocks, 256, 0, stream>>>(AGG, X, Wb1l, Wb1r, b1, HA);
    k_gather<<<gatherBlocks, 256, 0, stream>>>(HA, ell, cnt, AGG);
    k_linear<<<linearBlocks, 256, 0, stream>>>(AGG, HA, Wb2l, Wb2r, b2, HB);
    k_gather<<<gatherBlocks, 256, 0, stream>>>(HB, ell, cnt, AGG);
    k_linear<<<linearBlocks, 256, 0, stream>>>(AGG, HB, Wb3l, Wb3r, b3, HA);

    k_pool<<<N_GRAPHS, 256, 0, stream>>>(HA, batch, out);
}